// Round 1
// baseline (13924.384 us; speedup 1.0000x reference)
//
#include <hip/hip_runtime.h>
#include <hip/hip_bf16.h>

typedef unsigned short u16;
typedef __attribute__((ext_vector_type(8))) short bf16x8;
typedef __attribute__((ext_vector_type(4))) float f32x4;

// Problem sizes
#define HID 1024
#define BATCH 64
#define SEQ 512
#define MTOK 32768   // SEQ*BATCH

// Workspace layout (bytes unless noted)
#define WB_WIH0 0            // bf16 element offsets into weight area
#define WB_WHH0 4194304
#define WB_WIH1 8388608
#define WB_WHH1 12582912
#define WS_X_OFF   33554432ull           // X / hs0 buffer (bf16, 32768x1024)
#define WS_XP_OFF  100663296ull          // Xproj (bf16, 32768x4096)
#define WS_RING_OFF 369098752ull         // 2 x 64 x 1024 bf16 ring for layer1 h
#define WS_CTR_OFF 369360896ull          // barrier counters
#define WS_NEEDED  369361152ull

// Output layout (fp32 elements)
#define OUT_H_OFF 33554432
#define OUT_C_OFF 33685504

__device__ __forceinline__ u16 f2bf(float f) {
    union { float f; unsigned u; } x; x.f = f;
    unsigned r = (x.u + 0x7FFFu + ((x.u >> 16) & 1u)) >> 16;
    return (u16)r;
}
__device__ __forceinline__ float bf2f(u16 v) {
    union { unsigned u; float f; } x; x.u = ((unsigned)v) << 16;
    return x.f;
}
__device__ __forceinline__ float fexp2(float x) { return __builtin_amdgcn_exp2f(x); }
__device__ __forceinline__ float frcp(float x) { return __builtin_amdgcn_rcpf(x); }
__device__ __forceinline__ float sigm(float x) {
    return frcp(1.f + fexp2(x * -1.4426950408889634f));
}
__device__ __forceinline__ float tanh_f(float x) {
    // 1 - 2/(e^(2x)+1); saturates correctly at +-inf without NaN
    return 1.f - 2.f * frcp(fexp2(x * 2.8853900817779268f) + 1.f);
}

__device__ __forceinline__ void ldsload16(const u16* g, u16* l) {
    __builtin_amdgcn_global_load_lds(
        (__attribute__((address_space(1))) void*)(unsigned long long)(const char*)g,
        (__attribute__((address_space(3))) void*)l, 16, 0, 0);
}

// ---------------- prep: weights fp32->bf16, zero barrier counters ----------------
__launch_bounds__(256)
__global__ void prep_weights(const float* __restrict__ a, const float* __restrict__ b,
                             const float* __restrict__ c, const float* __restrict__ d,
                             u16* __restrict__ dst, unsigned* __restrict__ ctr) {
    if (blockIdx.x == 0 && threadIdx.x == 0) { ctr[0] = 0u; ctr[32] = 0u; }
    const int gtid = blockIdx.x * 256 + threadIdx.x;     // 262144 threads
#pragma unroll
    for (int k = 0; k < 16; k++) {
        const float* s = (k < 4) ? a : (k < 8) ? b : (k < 12) ? c : d;
        const int off = ((k & 3) * 262144 + gtid) * 4;   // element offset within matrix
        float4 v = *(const float4*)(s + off);
        ushort4 o;
        o.x = f2bf(v.x); o.y = f2bf(v.y); o.z = f2bf(v.z); o.w = f2bf(v.w);
        *(ushort4*)(dst + (size_t)(k >> 2) * 4194304 + off) = o;
    }
}

// ---------------- embedding gather: X[t*64+b][k] = bf16(E[y[b][t]][k]) ----------------
__launch_bounds__(256)
__global__ void gather_x(const int* __restrict__ y, const float* __restrict__ E,
                         u16* __restrict__ X) {
    const int m = blockIdx.x;           // 0..32767
    const int t = m >> 6, b = m & 63;
    const int idx = y[b * SEQ + t];
    const float4 v = *(const float4*)(E + (size_t)idx * HID + threadIdx.x * 4);
    ushort4 o;
    o.x = f2bf(v.x); o.y = f2bf(v.y); o.z = f2bf(v.z); o.w = f2bf(v.w);
    *(ushort4*)(X + (size_t)m * HID + threadIdx.x * 4) = o;
}

// ---------------- big GEMM: C[m][n] = bf16( A[m][:]·B[n][:] + bias[n] ) ----------------
// A: MxK bf16 row-major, B: NxK bf16 row-major (B^T form), 128x128 tile, BK=64
__launch_bounds__(256, 3)
__global__ void gemm_bt(const u16* __restrict__ A, const u16* __restrict__ Bm,
                        const float* __restrict__ bias, u16* __restrict__ C,
                        int M, int N, int K) {
    __shared__ u16 As[128 * 64];
    __shared__ u16 Bs[128 * 64];
    const int tid = threadIdx.x;
    const int ln = tid & 63;
    const int l15 = ln & 15, q = ln >> 4;
    const int w = tid >> 6;
    const int wm = (w & 1) * 64, wn = (w >> 1) * 64;
    const int m0 = blockIdx.y * 128, n0 = blockIdx.x * 128;

    f32x4 acc[4][4];
#pragma unroll
    for (int i = 0; i < 4; i++)
#pragma unroll
        for (int j = 0; j < 4; j++) acc[i][j] = 0.f;

    const int srow = tid >> 3;   // 0..31
    const int spk = tid & 7;
    const u16* gA = A + (size_t)m0 * K;
    const u16* gB = Bm + (size_t)n0 * K;
    const int wbase = (tid & 0xC0) * 8;   // wave-uniform LDS ushort offset

    const int kIters = K >> 6;
    for (int kt = 0; kt < kIters; kt++) {
        const int k0 = kt << 6;
        __syncthreads();
#pragma unroll
        for (int i = 0; i < 4; i++) {
            const int row = i * 32 + srow;
            const int kb = spk ^ (row & 7);          // XOR swizzle (global side)
            ldsload16(gA + (size_t)row * K + k0 + kb * 8, &As[i * 2048 + wbase]);
            ldsload16(gB + (size_t)row * K + k0 + kb * 8, &Bs[i * 2048 + wbase]);
        }
        __syncthreads();
#pragma unroll
        for (int s = 0; s < 2; s++) {
            const int xk = ((s * 4 + q) ^ (l15 & 7)) * 8;
            bf16x8 af[4], bfr[4];
#pragma unroll
            for (int mi = 0; mi < 4; mi++)
                af[mi] = *(const bf16x8*)&As[(wm + mi * 16 + l15) * 64 + xk];
#pragma unroll
            for (int nj = 0; nj < 4; nj++)
                bfr[nj] = *(const bf16x8*)&Bs[(wn + nj * 16 + l15) * 64 + xk];
#pragma unroll
            for (int mi = 0; mi < 4; mi++)
#pragma unroll
                for (int nj = 0; nj < 4; nj++)
                    acc[mi][nj] = __builtin_amdgcn_mfma_f32_16x16x32_bf16(
                        af[mi], bfr[nj], acc[mi][nj], 0, 0, 0);
        }
    }
    // epilogue: add bias, store bf16
#pragma unroll
    for (int nj = 0; nj < 4; nj++) {
        const int n = n0 + wn + nj * 16 + l15;
        const float bv = bias[n];
#pragma unroll
        for (int mi = 0; mi < 4; mi++) {
            const size_t m = (size_t)(m0 + wm + mi * 16 + q * 4);
            u16* cp = C + m * N + n;
            f32x4 v = acc[mi][nj];
            cp[0]           = f2bf(v.x + bv);
            cp[(size_t)N]   = f2bf(v.y + bv);
            cp[(size_t)2*N] = f2bf(v.z + bv);
            cp[(size_t)3*N] = f2bf(v.w + bv);
        }
    }
}

// ---------------- persistent LSTM recurrence ----------------
// 64 blocks, block bid owns units j0=bid*16 .. +15 (64 gate columns).
// Waves = K-quarters; Whh slice resident in VGPRs (wf[4][8], 128 VGPRs).
// Per step: h(t-1) from global -> MFMA -> LDS partial reduce -> elementwise -> barrier.
template <int IS_L1>
__launch_bounds__(256, 1)
__global__ void rec_kernel(const u16* __restrict__ Whh, const u16* __restrict__ Xp,
                           u16* __restrict__ hbuf, float* __restrict__ out,
                           unsigned* __restrict__ ctr) {
    __shared__ float P[4][64][64];   // 64 KB partials: [wave][col][m, XOR-swizzled in 4-blocks]
    const int tid = threadIdx.x;
    const int w = tid >> 6, ln = tid & 63;
    const int l15 = ln & 15, q = ln >> 4;
    const int j0 = blockIdx.x * 16;

    // Load Whh fragments into registers: wf[gate][ki], wave's K-range = [w*256, w*256+256)
    bf16x8 wf[4][8];
    {
        const u16* wbase = Whh + (size_t)(j0 + l15) * HID + w * 256 + q * 8;
#pragma unroll
        for (int nt = 0; nt < 4; nt++)
#pragma unroll
            for (int ki = 0; ki < 8; ki++)
                wf[nt][ki] = *(const bf16x8*)(wbase + (size_t)nt * 1048576 + ki * 32);
    }

    const int eu = tid >> 4;   // unit 0..15
    const int bq = tid & 15;   // batch quad
    f32x4 cst = 0.f;           // c-state for (b = bq*4 .. +3, unit eu)

    for (int t = 0; t < SEQ; t++) {
        // prefetch Xproj (precomputed, safe to read before barrier)
        float xpv[4][4];   // [gate][bb]
        {
            const u16* xr = Xp + (size_t)(t * 64 + bq * 4) * 4096 + j0 + eu;
#pragma unroll
            for (int bb = 0; bb < 4; bb++)
#pragma unroll
                for (int gg = 0; gg < 4; gg++)
                    xpv[gg][bb] = bf2f(xr[(size_t)bb * 4096 + gg * 1024]);
        }
        // wait for all blocks to finish step t-1 (device-scope)
        if (t > 0) {
            if (tid == 0) {
                const unsigned target = 64u * (unsigned)t;
                while (__hip_atomic_load(ctr, __ATOMIC_RELAXED, __HIP_MEMORY_SCOPE_AGENT) < target) {
                    __builtin_amdgcn_s_sleep(1);
                }
                __threadfence();   // acquire: invalidate L1/L2 before reading h(t-1)
            }
            __syncthreads();
        }
        if (t > 0) {
            f32x4 acc[4][4];
#pragma unroll
            for (int mt = 0; mt < 4; mt++)
#pragma unroll
                for (int nt = 0; nt < 4; nt++) acc[mt][nt] = 0.f;
            const u16* hbase = hbuf + (size_t)(IS_L1 ? ((t - 1) & 1) : (t - 1)) * 65536;
            const u16* arow = hbase + (size_t)l15 * HID + w * 256 + q * 8;
#pragma unroll
            for (int ki = 0; ki < 8; ki++) {
                bf16x8 a[4];
#pragma unroll
                for (int mt = 0; mt < 4; mt++)
                    a[mt] = *(const bf16x8*)(arow + mt * 16384 + ki * 32);
#pragma unroll
                for (int mt = 0; mt < 4; mt++)
#pragma unroll
                    for (int nt = 0; nt < 4; nt++)
                        acc[mt][nt] = __builtin_amdgcn_mfma_f32_16x16x32_bf16(
                            a[mt], wf[nt][ki], acc[mt][nt], 0, 0, 0);
            }
            // write partials to LDS (XOR swizzle on m-block keeps banks uniform)
#pragma unroll
            for (int mt = 0; mt < 4; mt++)
#pragma unroll
                for (int nt = 0; nt < 4; nt++) {
                    const int c = nt * 16 + l15;
                    const int phys = (mt * 4 + q) ^ (c & 7);
                    *(f32x4*)&P[w][c][phys * 4] = acc[mt][nt];
                }
        }
        __syncthreads();
        // elementwise: thread handles (unit eu, batches bq*4..+3)
        f32x4 pre[4];
        if (t > 0) {
#pragma unroll
            for (int gg = 0; gg < 4; gg++) {
                const int c = gg * 16 + eu;
                const int pb = (bq ^ (c & 7)) * 4;
                f32x4 s0 = *(const f32x4*)&P[0][c][pb];
                f32x4 s1 = *(const f32x4*)&P[1][c][pb];
                f32x4 s2 = *(const f32x4*)&P[2][c][pb];
                f32x4 s3 = *(const f32x4*)&P[3][c][pb];
                pre[gg] = (s0 + s1) + (s2 + s3);
            }
        } else {
#pragma unroll
            for (int gg = 0; gg < 4; gg++) pre[gg] = 0.f;
        }
        u16* hout = hbuf + (size_t)(IS_L1 ? (t & 1) : t) * 65536;
#pragma unroll
        for (int bb = 0; bb < 4; bb++) {
            const int b = bq * 4 + bb;
            const float pi = pre[0][bb] + xpv[0][bb];
            const float pf = pre[1][bb] + xpv[1][bb] + 1.0f;   // forget_gate_bias
            const float pg = pre[2][bb] + xpv[2][bb];
            const float po = pre[3][bb] + xpv[3][bb];
            const float gi = sigm(pi), gf = sigm(pf), gc = tanh_f(pg), go = sigm(po);
            const float cnew = gf * cst[bb] + gi * gc;
            cst[bb] = cnew;
            const float hnew = go * tanh_f(cnew);
            hout[(size_t)b * HID + j0 + eu] = f2bf(hnew);
            if (IS_L1)
                out[(size_t)b * 524288 + (size_t)t * 1024 + j0 + eu] = hnew;
            if (t == SEQ - 1) {
                out[OUT_H_OFF + IS_L1 * 65536 + (size_t)b * HID + j0 + eu] = hnew;
                out[OUT_C_OFF + IS_L1 * 65536 + (size_t)b * HID + j0 + eu] = cnew;
            }
        }
        __syncthreads();   // drains vmem stores of all waves before the release
        if (t < SEQ - 1 && tid == 0) {
            __threadfence();   // release: writeback L2 so other XCDs see h(t)
            __hip_atomic_fetch_add(ctr, 1u, __ATOMIC_RELAXED, __HIP_MEMORY_SCOPE_AGENT);
        }
    }
}

__global__ void diag(float* o, float v) { o[0] = v; }

extern "C" void kernel_launch(void* const* d_in, const int* in_sizes, int n_in,
                              void* d_out, int out_size, void* d_ws, size_t ws_size,
                              hipStream_t stream) {
    const int*   y    = (const int*)  d_in[0];
    const float* Emb  = (const float*)d_in[1];
    const float* Wih0 = (const float*)d_in[2];
    const float* Whh0 = (const float*)d_in[3];
    const float* b0   = (const float*)d_in[4];
    const float* Wih1 = (const float*)d_in[5];
    const float* Whh1 = (const float*)d_in[6];
    const float* b1   = (const float*)d_in[7];
    float* out = (float*)d_out;
    char* wsb = (char*)d_ws;

    if (ws_size < WS_NEEDED) {   // diagnostic: encode ws MB into out[0]
        diag<<<1, 1, 0, stream>>>(out, (float)(ws_size >> 20));
        return;
    }

    u16* wb   = (u16*)wsb;
    u16* X    = (u16*)(wsb + WS_X_OFF);
    u16* Xp   = (u16*)(wsb + WS_XP_OFF);
    u16* ring = (u16*)(wsb + WS_RING_OFF);
    unsigned* ctr = (unsigned*)(wsb + WS_CTR_OFF);

    prep_weights<<<1024, 256, 0, stream>>>(Wih0, Whh0, Wih1, Whh1, wb, ctr);
    gather_x<<<MTOK, 256, 0, stream>>>(y, Emb, X);
    // layer 0: input projection + recurrence (hs0 written into X buffer)
    gemm_bt<<<dim3(32, 256), 256, 0, stream>>>(X, wb + WB_WIH0, b0, Xp, MTOK, 4096, HID);
    rec_kernel<0><<<64, 256, 0, stream>>>(wb + WB_WHH0, Xp, X, out, ctr + 0);
    // layer 1: input projection from hs0 + recurrence (g -> d_out)
    gemm_bt<<<dim3(32, 256), 256, 0, stream>>>(X, wb + WB_WIH1, b1, Xp, MTOK, 4096, HID);
    rec_kernel<1><<<64, 256, 0, stream>>>(wb + WB_WHH1, Xp, ring, out, ctr + 32);
}

// Round 2
// 10549.005 us; speedup vs baseline: 1.3200x; 1.3200x over previous
//
#include <hip/hip_runtime.h>
#include <hip/hip_bf16.h>

typedef unsigned short u16;
typedef unsigned long long ull;
typedef __attribute__((ext_vector_type(8))) short bf16x8;
typedef __attribute__((ext_vector_type(4))) float f32x4;
typedef __attribute__((ext_vector_type(2))) float f32x2;

// Problem sizes
#define HID 1024
#define BATCH 64
#define SEQ 512
#define MTOK 32768   // SEQ*BATCH

// Workspace layout
#define WB_WIH0 0            // bf16 element offsets into weight area
#define WB_WHH0 4194304
#define WB_WIH1 8388608
#define WB_WHH1 12582912
#define WS_X_OFF   33554432ull           // X / hs0 buffer (bf16, 32768x1024)
#define WS_XP_OFF  100663296ull          // Xproj (bf16, 32768x4096)
#define WS_CTR_OFF 369360896ull          // barrier counters
#define WS_NEEDED  369361152ull
// h-exchange rings overlay dead weight regions:
//   ring0 (layer0): bytes [0, 256K)        = Wih0 bf16 area, dead after gemm0
//   ring1 (layer1): bytes [8M, 8M+256K)    = Whh0 bf16 area, dead after rec<0>
#define RING0_BYTE 0ull
#define RING1_BYTE 8388608ull

// Output layout (fp32 elements)
#define OUT_H_OFF 33554432
#define OUT_C_OFF 33685504

__device__ __forceinline__ u16 f2bf(float f) {
    union { float f; unsigned u; } x; x.f = f;
    unsigned r = (x.u + 0x7FFFu + ((x.u >> 16) & 1u)) >> 16;
    return (u16)r;
}
__device__ __forceinline__ float bf2f(u16 v) {
    union { unsigned u; float f; } x; x.u = ((unsigned)v) << 16;
    return x.f;
}
__device__ __forceinline__ float fexp2(float x) { return __builtin_amdgcn_exp2f(x); }
__device__ __forceinline__ float frcp(float x) { return __builtin_amdgcn_rcpf(x); }
__device__ __forceinline__ float sigm(float x) {
    return frcp(1.f + fexp2(x * -1.4426950408889634f));
}
__device__ __forceinline__ float tanh_f(float x) {
    return 1.f - 2.f * frcp(fexp2(x * 2.8853900817779268f) + 1.f);
}
__device__ __forceinline__ float xhalf(unsigned r, int u) {
    return bf2f(u ? (u16)(r >> 16) : (u16)(r & 0xffffu));
}

__device__ __forceinline__ void ldsload16(const u16* g, u16* l) {
    __builtin_amdgcn_global_load_lds(
        (__attribute__((address_space(1))) void*)(unsigned long long)(const char*)g,
        (__attribute__((address_space(3))) void*)l, 16, 0, 0);
}

// ---------------- prep: weights fp32->bf16, zero barrier counters ----------------
__launch_bounds__(256)
__global__ void prep_weights(const float* __restrict__ a, const float* __restrict__ b,
                             const float* __restrict__ c, const float* __restrict__ d,
                             u16* __restrict__ dst, unsigned* __restrict__ ctr) {
    if (blockIdx.x == 0 && threadIdx.x == 0) { ctr[0] = 0u; ctr[32] = 0u; }
    const int gtid = blockIdx.x * 256 + threadIdx.x;
#pragma unroll
    for (int k = 0; k < 16; k++) {
        const float* s = (k < 4) ? a : (k < 8) ? b : (k < 12) ? c : d;
        const int off = ((k & 3) * 262144 + gtid) * 4;
        float4 v = *(const float4*)(s + off);
        ushort4 o;
        o.x = f2bf(v.x); o.y = f2bf(v.y); o.z = f2bf(v.z); o.w = f2bf(v.w);
        *(ushort4*)(dst + (size_t)(k >> 2) * 4194304 + off) = o;
    }
}

// ---------------- embedding gather ----------------
__launch_bounds__(256)
__global__ void gather_x(const int* __restrict__ y, const float* __restrict__ E,
                         u16* __restrict__ X) {
    const int m = blockIdx.x;
    const int t = m >> 6, b = m & 63;
    const int idx = y[b * SEQ + t];
    const float4 v = *(const float4*)(E + (size_t)idx * HID + threadIdx.x * 4);
    ushort4 o;
    o.x = f2bf(v.x); o.y = f2bf(v.y); o.z = f2bf(v.z); o.w = f2bf(v.w);
    *(ushort4*)(X + (size_t)m * HID + threadIdx.x * 4) = o;
}

// ---------------- big GEMM: C[m][n] = bf16( A[m][:]·B[n][:] + bias[n] ) ----------------
__launch_bounds__(256, 3)
__global__ void gemm_bt(const u16* __restrict__ A, const u16* __restrict__ Bm,
                        const float* __restrict__ bias, u16* __restrict__ C,
                        int M, int N, int K) {
    __shared__ u16 As[128 * 64];
    __shared__ u16 Bs[128 * 64];
    const int tid = threadIdx.x;
    const int ln = tid & 63;
    const int l15 = ln & 15, q = ln >> 4;
    const int w = tid >> 6;
    const int wm = (w & 1) * 64, wn = (w >> 1) * 64;
    const int m0 = blockIdx.y * 128, n0 = blockIdx.x * 128;

    f32x4 acc[4][4];
#pragma unroll
    for (int i = 0; i < 4; i++)
#pragma unroll
        for (int j = 0; j < 4; j++) acc[i][j] = 0.f;

    const int srow = tid >> 3;
    const int spk = tid & 7;
    const u16* gA = A + (size_t)m0 * K;
    const u16* gB = Bm + (size_t)n0 * K;
    const int wbase = (tid & 0xC0) * 8;

    const int kIters = K >> 6;
    for (int kt = 0; kt < kIters; kt++) {
        const int k0 = kt << 6;
        __syncthreads();
#pragma unroll
        for (int i = 0; i < 4; i++) {
            const int row = i * 32 + srow;
            const int kb = spk ^ (row & 7);
            ldsload16(gA + (size_t)row * K + k0 + kb * 8, &As[i * 2048 + wbase]);
            ldsload16(gB + (size_t)row * K + k0 + kb * 8, &Bs[i * 2048 + wbase]);
        }
        __syncthreads();
#pragma unroll
        for (int s = 0; s < 2; s++) {
            const int xk = ((s * 4 + q) ^ (l15 & 7)) * 8;
            bf16x8 af[4], bfr[4];
#pragma unroll
            for (int mi = 0; mi < 4; mi++)
                af[mi] = *(const bf16x8*)&As[(wm + mi * 16 + l15) * 64 + xk];
#pragma unroll
            for (int nj = 0; nj < 4; nj++)
                bfr[nj] = *(const bf16x8*)&Bs[(wn + nj * 16 + l15) * 64 + xk];
#pragma unroll
            for (int mi = 0; mi < 4; mi++)
#pragma unroll
                for (int nj = 0; nj < 4; nj++)
                    acc[mi][nj] = __builtin_amdgcn_mfma_f32_16x16x32_bf16(
                        af[mi], bfr[nj], acc[mi][nj], 0, 0, 0);
        }
    }
#pragma unroll
    for (int nj = 0; nj < 4; nj++) {
        const int n = n0 + wn + nj * 16 + l15;
        const float bv = bias[n];
#pragma unroll
        for (int mi = 0; mi < 4; mi++) {
            const size_t m = (size_t)(m0 + wm + mi * 16 + q * 4);
            u16* cp = C + m * N + n;
            f32x4 v = acc[mi][nj];
            cp[0]           = f2bf(v.x + bv);
            cp[(size_t)N]   = f2bf(v.y + bv);
            cp[(size_t)2*N] = f2bf(v.z + bv);
            cp[(size_t)3*N] = f2bf(v.w + bv);
        }
    }
}

// ---------------- persistent LSTM recurrence ----------------
// 64 blocks; block owns units j0..j0+15 (64 gate cols). Whh slice in VGPRs.
// Cross-block h exchange: sc1 (device-coherent) stores/loads on a 2-slot ring
// through the memory-side LLC — NO threadfence / L2 flush anywhere.
template <int IS_L1>
__launch_bounds__(256, 1)
__global__ void rec_kernel(const u16* __restrict__ Whh, const u16* __restrict__ Xp,
                           u16* __restrict__ ring, u16* __restrict__ hs0,
                           float* __restrict__ out, unsigned* __restrict__ ctr) {
    __shared__ float P[4][64][64];   // 64 KB partials [wave][col][m phys-swizzled]
    const int tid = threadIdx.x;
    const int w = tid >> 6, ln = tid & 63;
    const int l15 = ln & 15, q = ln >> 4;
    const int j0 = blockIdx.x * 16;

    // Whh fragments resident in registers: wave's K-range = [w*256, w*256+256)
    bf16x8 wf[4][8];
    {
        const u16* wbase = Whh + (size_t)(j0 + l15) * HID + w * 256 + q * 8;
#pragma unroll
        for (int nt = 0; nt < 4; nt++)
#pragma unroll
            for (int ki = 0; ki < 8; ki++)
                wf[nt][ki] = *(const bf16x8*)(wbase + (size_t)nt * 1048576 + ki * 32);
    }

    const int up = tid & 7;    // unit pair: units 2up, 2up+1
    const int bp = tid >> 3;   // batch pair: batches 2bp, 2bp+1
    float cst[2][2] = {{0.f, 0.f}, {0.f, 0.f}};   // [bb][u]

    for (int t = 0; t < SEQ; t++) {
        // prefetch Xproj raw (no conversion -> no waitcnt before the poll)
        unsigned xraw[4][2];   // [gate][bb]
        {
            const u16* xr = Xp + (size_t)(t * 64 + bp * 2) * 4096 + j0 + up * 2;
#pragma unroll
            for (int bb = 0; bb < 2; bb++)
#pragma unroll
                for (int gg = 0; gg < 4; gg++)
                    xraw[gg][bb] = *(const unsigned*)(xr + (size_t)bb * 4096 + gg * 1024);
        }
        if (t > 0) {
            if (tid == 0) {
                const unsigned target = 64u * (unsigned)t;
                while (__hip_atomic_load(ctr, __ATOMIC_RELAXED, __HIP_MEMORY_SCOPE_AGENT) < target) {
                    __builtin_amdgcn_s_sleep(1);
                }
            }
            __syncthreads();
            // ---- MFMA: h(t-1) via device-coherent loads, double-buffered ki loop ----
            f32x4 acc[4][4];
#pragma unroll
            for (int mt = 0; mt < 4; mt++)
#pragma unroll
                for (int nt = 0; nt < 4; nt++) acc[mt][nt] = 0.f;
            const u16* hb = ring + (size_t)((t - 1) & 1) * 65536;
            const u16* arow = hb + (size_t)l15 * HID + w * 256 + q * 8;
            union BU { ull v[2]; bf16x8 f; };
            BU cb[4], nb[4];
#pragma unroll
            for (int mt = 0; mt < 4; mt++) {
                const ull* p = (const ull*)(arow + mt * 16384);
                cb[mt].v[0] = __hip_atomic_load(p,     __ATOMIC_RELAXED, __HIP_MEMORY_SCOPE_AGENT);
                cb[mt].v[1] = __hip_atomic_load(p + 1, __ATOMIC_RELAXED, __HIP_MEMORY_SCOPE_AGENT);
            }
#pragma unroll
            for (int ki = 0; ki < 8; ki++) {
                if (ki < 7) {
#pragma unroll
                    for (int mt = 0; mt < 4; mt++) {
                        const ull* p = (const ull*)(arow + mt * 16384 + (ki + 1) * 32);
                        nb[mt].v[0] = __hip_atomic_load(p,     __ATOMIC_RELAXED, __HIP_MEMORY_SCOPE_AGENT);
                        nb[mt].v[1] = __hip_atomic_load(p + 1, __ATOMIC_RELAXED, __HIP_MEMORY_SCOPE_AGENT);
                    }
                }
#pragma unroll
                for (int mt = 0; mt < 4; mt++)
#pragma unroll
                    for (int nt = 0; nt < 4; nt++)
                        acc[mt][nt] = __builtin_amdgcn_mfma_f32_16x16x32_bf16(
                            cb[mt].f, wf[nt][ki], acc[mt][nt], 0, 0, 0);
#pragma unroll
                for (int mt = 0; mt < 4; mt++) {
                    cb[mt].v[0] = nb[mt].v[0];
                    cb[mt].v[1] = nb[mt].v[1];
                }
            }
            // partials to LDS (XOR swizzle on m-block)
#pragma unroll
            for (int mt = 0; mt < 4; mt++)
#pragma unroll
                for (int nt = 0; nt < 4; nt++) {
                    const int c = nt * 16 + l15;
                    const int phys = (mt * 4 + q) ^ (c & 7);
                    *(f32x4*)&P[w][c][phys * 4] = acc[mt][nt];
                }
        }
        __syncthreads();
        // ---- elementwise: thread = (unit pair up, batch pair bp) ----
        f32x2 pre[4][2];   // [gate][u], component = bb
        if (t > 0) {
#pragma unroll
            for (int gg = 0; gg < 4; gg++)
#pragma unroll
                for (int u = 0; u < 2; u++) {
                    const int col = gg * 16 + up * 2 + u;
                    const int base = (((bp >> 1) ^ (col & 7)) << 2) | ((bp & 1) << 1);
                    f32x2 s = *(const f32x2*)&P[0][col][base];
                    s += *(const f32x2*)&P[1][col][base];
                    s += *(const f32x2*)&P[2][col][base];
                    s += *(const f32x2*)&P[3][col][base];
                    pre[gg][u] = s;
                }
        } else {
#pragma unroll
            for (int gg = 0; gg < 4; gg++)
#pragma unroll
                for (int u = 0; u < 2; u++) pre[gg][u] = 0.f;
        }
        float hn[2][2], cn[2][2];
#pragma unroll
        for (int bb = 0; bb < 2; bb++)
#pragma unroll
            for (int u = 0; u < 2; u++) {
                const float pi = pre[0][u][bb] + xhalf(xraw[0][bb], u);
                const float pf = pre[1][u][bb] + xhalf(xraw[1][bb], u) + 1.0f;  // FGB
                const float pg = pre[2][u][bb] + xhalf(xraw[2][bb], u);
                const float po = pre[3][u][bb] + xhalf(xraw[3][bb], u);
                const float gi = sigm(pi), gf = sigm(pf), gc = tanh_f(pg), go = sigm(po);
                const float cnew = gf * cst[bb][u] + gi * gc;
                cst[bb][u] = cnew;
                hn[bb][u] = go * tanh_f(cnew);
                cn[bb][u] = cnew;
            }
        u16* hout = ring + (size_t)(t & 1) * 65536;
#pragma unroll
        for (int bb = 0; bb < 2; bb++) {
            const int b = bp * 2 + bb;
            const unsigned hw = (unsigned)f2bf(hn[bb][0]) | ((unsigned)f2bf(hn[bb][1]) << 16);
            __hip_atomic_store((unsigned*)(hout + (size_t)b * HID + j0 + up * 2), hw,
                               __ATOMIC_RELAXED, __HIP_MEMORY_SCOPE_AGENT);
            if (!IS_L1)   // archive hs0 for gemm1 (normal store, flushed at kernel end)
                *(unsigned*)(hs0 + (size_t)(t * 64 + b) * HID + j0 + up * 2) = hw;
            if (IS_L1) {
                f32x2 g2 = {hn[bb][0], hn[bb][1]};
                *(f32x2*)&out[(size_t)b * 524288 + (size_t)t * 1024 + j0 + up * 2] = g2;
            }
            if (t == SEQ - 1) {
                f32x2 h2 = {hn[bb][0], hn[bb][1]};
                f32x2 c2 = {cn[bb][0], cn[bb][1]};
                *(f32x2*)&out[OUT_H_OFF + IS_L1 * 65536 + (size_t)b * HID + j0 + up * 2] = h2;
                *(f32x2*)&out[OUT_C_OFF + IS_L1 * 65536 + (size_t)b * HID + j0 + up * 2] = c2;
            }
        }
        __syncthreads();   // per-wave vmcnt(0) drain: sc1 stores at LLC before flag
        if (t < SEQ - 1 && tid == 0) {
            __hip_atomic_fetch_add(ctr, 1u, __ATOMIC_RELAXED, __HIP_MEMORY_SCOPE_AGENT);
        }
    }
}

__global__ void diag(float* o, float v) { o[0] = v; }

extern "C" void kernel_launch(void* const* d_in, const int* in_sizes, int n_in,
                              void* d_out, int out_size, void* d_ws, size_t ws_size,
                              hipStream_t stream) {
    const int*   y    = (const int*)  d_in[0];
    const float* Emb  = (const float*)d_in[1];
    const float* Wih0 = (const float*)d_in[2];
    const float* Whh0 = (const float*)d_in[3];
    const float* b0   = (const float*)d_in[4];
    const float* Wih1 = (const float*)d_in[5];
    const float* Whh1 = (const float*)d_in[6];
    const float* b1   = (const float*)d_in[7];
    float* out = (float*)d_out;
    char* wsb = (char*)d_ws;

    if (ws_size < WS_NEEDED) {
        diag<<<1, 1, 0, stream>>>(out, (float)(ws_size >> 20));
        return;
    }

    u16* wb   = (u16*)wsb;
    u16* X    = (u16*)(wsb + WS_X_OFF);
    u16* Xp   = (u16*)(wsb + WS_XP_OFF);
    u16* ring0 = (u16*)(wsb + RING0_BYTE);   // overlays Wih0 (dead after gemm0)
    u16* ring1 = (u16*)(wsb + RING1_BYTE);   // overlays Whh0 (dead after rec<0>)
    unsigned* ctr = (unsigned*)(wsb + WS_CTR_OFF);

    prep_weights<<<1024, 256, 0, stream>>>(Wih0, Whh0, Wih1, Whh1, wb, ctr);
    gather_x<<<MTOK, 256, 0, stream>>>(y, Emb, X);
    gemm_bt<<<dim3(32, 256), 256, 0, stream>>>(X, wb + WB_WIH0, b0, Xp, MTOK, 4096, HID);
    rec_kernel<0><<<64, 256, 0, stream>>>(wb + WB_WHH0, Xp, ring0, X, out, ctr + 0);
    gemm_bt<<<dim3(32, 256), 256, 0, stream>>>(X, wb + WB_WIH1, b1, Xp, MTOK, 4096, HID);
    rec_kernel<1><<<64, 256, 0, stream>>>(wb + WB_WHH1, Xp, ring1, X, out, ctr + 32);
}

// Round 3
// 6812.679 us; speedup vs baseline: 2.0439x; 1.5484x over previous
//
#include <hip/hip_runtime.h>
#include <hip/hip_bf16.h>

typedef unsigned short u16;
typedef unsigned long long ull;
typedef __attribute__((ext_vector_type(8))) short bf16x8;
typedef __attribute__((ext_vector_type(4))) float f32x4;
typedef __attribute__((ext_vector_type(2))) float f32x2;

// Problem sizes
#define HID 1024
#define BATCH 64
#define SEQ 512
#define MTOK 32768   // SEQ*BATCH

// Workspace layout (bytes)
// Weight area: 4 matrices x 8 MB bf16 = [0, 32M). Element offsets (u16):
#define WB_WIH0 0
#define WB_WHH0 4194304
#define WB_WIH1 8388608
#define WB_WHH1 12582912
#define WS_X_OFF   33554432ull           // X buffer (bf16, 32768x1024)
#define WS_XP_OFF  100663296ull          // Xproj layer0 (bf16, 32768x4096)
#define WS_NEEDED  369098752ull
// Rings + flags overlay the Wih0 bf16 byte region [0, 8M), dead after gemm0:
#define RING0_B 0ull          // 4 slots x 64x1024 bf16 = 512 KB
#define RING1_B 524288ull     // 4 slots x 64x1024 bf16
#define XP1_B   1048576ull    // 4 slots x [4096 cols][64 batch] bf16 = 2 MB
#define FLAGS_B 3145728ull    // F0[64], Fp[64], Fr[64]

// Output layout (fp32 elements)
#define OUT_H_OFF 33554432
#define OUT_C_OFF 33685504

__device__ __forceinline__ u16 f2bf(float f) {
    union { float f; unsigned u; } x; x.f = f;
    unsigned r = (x.u + 0x7FFFu + ((x.u >> 16) & 1u)) >> 16;
    return (u16)r;
}
__device__ __forceinline__ float bf2f(u16 v) {
    union { unsigned u; float f; } x; x.u = ((unsigned)v) << 16;
    return x.f;
}
__device__ __forceinline__ float fexp2(float x) { return __builtin_amdgcn_exp2f(x); }
__device__ __forceinline__ float frcp(float x) { return __builtin_amdgcn_rcpf(x); }
__device__ __forceinline__ float sigm(float x) {
    return frcp(1.f + fexp2(x * -1.4426950408889634f));
}
__device__ __forceinline__ float tanh_f(float x) {
    return 1.f - 2.f * frcp(fexp2(x * 2.8853900817779268f) + 1.f);
}
__device__ __forceinline__ float xhalf(unsigned r, int u) {
    return bf2f(u ? (u16)(r >> 16) : (u16)(r & 0xffffu));
}
__device__ __forceinline__ void ldsload16(const u16* g, u16* l) {
    __builtin_amdgcn_global_load_lds(
        (__attribute__((address_space(1))) void*)(unsigned long long)(const char*)g,
        (__attribute__((address_space(3))) void*)l, 16, 0, 0);
}
__device__ __forceinline__ ull ld8(const ull* p) {
    return __hip_atomic_load(p, __ATOMIC_RELAXED, __HIP_MEMORY_SCOPE_AGENT);
}
__device__ __forceinline__ unsigned ld4(const unsigned* p) {
    return __hip_atomic_load(p, __ATOMIC_RELAXED, __HIP_MEMORY_SCOPE_AGENT);
}
__device__ __forceinline__ void st8(ull* p, ull v) {
    __hip_atomic_store(p, v, __ATOMIC_RELAXED, __HIP_MEMORY_SCOPE_AGENT);
}
__device__ __forceinline__ void st4(unsigned* p, unsigned v) {
    __hip_atomic_store(p, v, __ATOMIC_RELAXED, __HIP_MEMORY_SCOPE_AGENT);
}

// ---------------- prep: weights fp32->bf16 ----------------
__launch_bounds__(256)
__global__ void prep_weights(const float* __restrict__ a, const float* __restrict__ b,
                             const float* __restrict__ c, const float* __restrict__ d,
                             u16* __restrict__ dst) {
    const int gtid = blockIdx.x * 256 + threadIdx.x;
#pragma unroll
    for (int k = 0; k < 16; k++) {
        const float* s = (k < 4) ? a : (k < 8) ? b : (k < 12) ? c : d;
        const int off = ((k & 3) * 262144 + gtid) * 4;
        float4 v = *(const float4*)(s + off);
        ushort4 o;
        o.x = f2bf(v.x); o.y = f2bf(v.y); o.z = f2bf(v.z); o.w = f2bf(v.w);
        *(ushort4*)(dst + (size_t)(k >> 2) * 4194304 + off) = o;
    }
}

// ---------------- embedding gather ----------------
__launch_bounds__(256)
__global__ void gather_x(const int* __restrict__ y, const float* __restrict__ E,
                         u16* __restrict__ X) {
    const int m = blockIdx.x;
    const int t = m >> 6, b = m & 63;
    const int idx = y[b * SEQ + t];
    const float4 v = *(const float4*)(E + (size_t)idx * HID + threadIdx.x * 4);
    ushort4 o;
    o.x = f2bf(v.x); o.y = f2bf(v.y); o.z = f2bf(v.z); o.w = f2bf(v.w);
    *(ushort4*)(X + (size_t)m * HID + threadIdx.x * 4) = o;
}

// ---------------- big GEMM (layer0 input projection) ----------------
__launch_bounds__(256, 3)
__global__ void gemm_bt(const u16* __restrict__ A, const u16* __restrict__ Bm,
                        const float* __restrict__ bias, u16* __restrict__ C,
                        int M, int N, int K) {
    __shared__ u16 As[128 * 64];
    __shared__ u16 Bs[128 * 64];
    const int tid = threadIdx.x;
    const int ln = tid & 63;
    const int l15 = ln & 15, q = ln >> 4;
    const int w = tid >> 6;
    const int wm = (w & 1) * 64, wn = (w >> 1) * 64;
    const int m0 = blockIdx.y * 128, n0 = blockIdx.x * 128;

    f32x4 acc[4][4];
#pragma unroll
    for (int i = 0; i < 4; i++)
#pragma unroll
        for (int j = 0; j < 4; j++) acc[i][j] = 0.f;

    const int srow = tid >> 3;
    const int spk = tid & 7;
    const u16* gA = A + (size_t)m0 * K;
    const u16* gB = Bm + (size_t)n0 * K;
    const int wbase = (tid & 0xC0) * 8;

    const int kIters = K >> 6;
    for (int kt = 0; kt < kIters; kt++) {
        const int k0 = kt << 6;
        __syncthreads();
#pragma unroll
        for (int i = 0; i < 4; i++) {
            const int row = i * 32 + srow;
            const int kb = spk ^ (row & 7);
            ldsload16(gA + (size_t)row * K + k0 + kb * 8, &As[i * 2048 + wbase]);
            ldsload16(gB + (size_t)row * K + k0 + kb * 8, &Bs[i * 2048 + wbase]);
        }
        __syncthreads();
#pragma unroll
        for (int s = 0; s < 2; s++) {
            const int xk = ((s * 4 + q) ^ (l15 & 7)) * 8;
            bf16x8 af[4], bfr[4];
#pragma unroll
            for (int mi = 0; mi < 4; mi++)
                af[mi] = *(const bf16x8*)&As[(wm + mi * 16 + l15) * 64 + xk];
#pragma unroll
            for (int nj = 0; nj < 4; nj++)
                bfr[nj] = *(const bf16x8*)&Bs[(wn + nj * 16 + l15) * 64 + xk];
#pragma unroll
            for (int mi = 0; mi < 4; mi++)
#pragma unroll
                for (int nj = 0; nj < 4; nj++)
                    acc[mi][nj] = __builtin_amdgcn_mfma_f32_16x16x32_bf16(
                        af[mi], bfr[nj], acc[mi][nj], 0, 0, 0);
        }
    }
#pragma unroll
    for (int nj = 0; nj < 4; nj++) {
        const int n = n0 + wn + nj * 16 + l15;
        const float bv = bias[n];
#pragma unroll
        for (int mi = 0; mi < 4; mi++) {
            const size_t m = (size_t)(m0 + wm + mi * 16 + q * 4);
            u16* cp = C + m * N + n;
            f32x4 v = acc[mi][nj];
            cp[0]           = f2bf(v.x + bv);
            cp[(size_t)N]   = f2bf(v.y + bv);
            cp[(size_t)2*N] = f2bf(v.z + bv);
            cp[(size_t)3*N] = f2bf(v.w + bv);
        }
    }
}

__global__ void init_flags(unsigned* f) { if (threadIdx.x < 192) f[threadIdx.x] = 0; }

// ---------------- fused persistent pipeline ----------------
// 192 blocks: role 0 = L0 recurrence, role 1 = P1 (Wih1 @ hs0 projection),
// role 2 = R1 recurrence. Flat per-block flag barrier (plain sc1 stores, 64-lane
// vector poll). 4-slot rings through LLC. No fences, no atomics RMW.

__device__ __forceinline__ void load_wf(const u16* W, int j0, int w, int l15, int q,
                                        bf16x8 wf[4][8]) {
    const u16* wbase = W + (size_t)(j0 + l15) * HID + w * 256 + q * 8;
#pragma unroll
    for (int nt = 0; nt < 4; nt++)
#pragma unroll
        for (int ki = 0; ki < 8; ki++)
            wf[nt][ki] = *(const bf16x8*)(wbase + (size_t)nt * 1048576 + ki * 32);
}

// A (64x1024 bf16 slab in LLC, sc1 loads, fully issued upfront) x wf -> P partials
__device__ __forceinline__ void mm_ring(const u16* slab, const bf16x8 wf[4][8],
                                        int w, int l15, int q, float (*P)[64][68]) {
    union BU { ull v[2]; bf16x8 f; };
    BU st[4][8];
    const u16* arow = slab + (size_t)l15 * HID + w * 256 + q * 8;
#pragma unroll
    for (int ki = 0; ki < 8; ki++)
#pragma unroll
        for (int mt = 0; mt < 4; mt++) {
            const ull* p = (const ull*)(arow + mt * 16384 + ki * 32);
            st[mt][ki].v[0] = ld8(p);
            st[mt][ki].v[1] = ld8(p + 1);
        }
    f32x4 acc[4][4];
#pragma unroll
    for (int mt = 0; mt < 4; mt++)
#pragma unroll
        for (int nt = 0; nt < 4; nt++) acc[mt][nt] = 0.f;
#pragma unroll
    for (int ki = 0; ki < 8; ki++)
#pragma unroll
        for (int mt = 0; mt < 4; mt++)
#pragma unroll
            for (int nt = 0; nt < 4; nt++)
                acc[mt][nt] = __builtin_amdgcn_mfma_f32_16x16x32_bf16(
                    st[mt][ki].f, wf[nt][ki], acc[mt][nt], 0, 0, 0);
#pragma unroll
    for (int mt = 0; mt < 4; mt++)
#pragma unroll
        for (int nt = 0; nt < 4; nt++)
            *(f32x4*)&P[w][nt * 16 + l15][mt * 16 + q * 4] = acc[mt][nt];
}

__device__ __forceinline__ void waitflags(const unsigned* F0, const unsigned* Fp,
                                          const unsigned* Fr, int n0, int np, int nr,
                                          int w, int ln, int* abortf) {
    const unsigned* A = (w == 0) ? F0 : (w == 1) ? Fp : Fr;
    const int need = (w == 0) ? n0 : (w == 1) ? np : nr;
    if (w < 3 && need > 0 && *abortf == 0) {
        int it = 0;
        while ((int)ld4(&A[ln]) < need) {
            if (++it > 20000000) { *abortf = 1; break; }
        }
    }
    __syncthreads();
}

__launch_bounds__(256, 1)
__global__ void pipeline(const u16* __restrict__ wb, const u16* __restrict__ Xp,
                         const float* __restrict__ b1, float* __restrict__ out,
                         u16* __restrict__ ring0, u16* __restrict__ ring1,
                         u16* __restrict__ xp1, unsigned* __restrict__ flags) {
    __shared__ float P[4][64][68];
    __shared__ int abortf;
    const int tid = threadIdx.x;
    if (tid == 0) abortf = 0;
    const int w = tid >> 6, ln = tid & 63;
    const int l15 = ln & 15, q = ln >> 4;
    const int bid = blockIdx.x;
    const int role = bid >> 6;
    const int j0 = (bid & 63) * 16;
    unsigned* F0 = flags;
    unsigned* Fp = flags + 64;
    unsigned* Fr = flags + 128;
    __syncthreads();

    bf16x8 wf[4][8];

    if (role == 0) {
        // ---------------- L0: h0(r) = lstm(Whh0 @ h0(r-1) + Xp(r)) ----------------
        load_wf(wb + WB_WHH0, j0, w, l15, q, wf);
        const int up = tid & 7, bp = tid >> 3;
        float cst[2][2] = {{0.f, 0.f}, {0.f, 0.f}};
        for (int r = 0; r < 512; ++r) {
            unsigned xraw[4][2];
            const u16* xr = Xp + (size_t)(r * 64 + bp * 2) * 4096 + j0 + up * 2;
#pragma unroll
            for (int bb = 0; bb < 2; bb++)
#pragma unroll
                for (int gg = 0; gg < 4; gg++)
                    xraw[gg][bb] = *(const unsigned*)(xr + (size_t)bb * 4096 + gg * 1024);
            waitflags(F0, Fp, Fr, r, r - 2, 0, w, ln, &abortf);
            if (r > 0)
                mm_ring(ring0 + (size_t)((r - 1) & 3) * 65536, wf, w, l15, q, P);
            __syncthreads();
            f32x2 pre[4][2];
#pragma unroll
            for (int gg = 0; gg < 4; gg++)
#pragma unroll
                for (int u = 0; u < 2; u++) {
                    if (r > 0) {
                        const int col = gg * 16 + up * 2 + u;
                        f32x2 s = *(const f32x2*)&P[0][col][bp * 2];
                        s += *(const f32x2*)&P[1][col][bp * 2];
                        s += *(const f32x2*)&P[2][col][bp * 2];
                        s += *(const f32x2*)&P[3][col][bp * 2];
                        pre[gg][u] = s;
                    } else pre[gg][u] = 0.f;
                }
            u16* hout = ring0 + (size_t)(r & 3) * 65536;
#pragma unroll
            for (int bb = 0; bb < 2; bb++) {
                const int b = bp * 2 + bb;
                float hn[2], cn[2];
#pragma unroll
                for (int u = 0; u < 2; u++) {
                    const float pi = pre[0][u][bb] + xhalf(xraw[0][bb], u);
                    const float pf = pre[1][u][bb] + xhalf(xraw[1][bb], u) + 1.0f;
                    const float pg = pre[2][u][bb] + xhalf(xraw[2][bb], u);
                    const float po = pre[3][u][bb] + xhalf(xraw[3][bb], u);
                    const float cnew = sigm(pf) * cst[bb][u] + sigm(pi) * tanh_f(pg);
                    cst[bb][u] = cnew;
                    hn[u] = sigm(po) * tanh_f(cnew);
                    cn[u] = cnew;
                }
                const unsigned hw = (unsigned)f2bf(hn[0]) | ((unsigned)f2bf(hn[1]) << 16);
                st4((unsigned*)(hout + (size_t)b * HID + j0 + up * 2), hw);
                if (r == 511) {
                    f32x2 h2 = {hn[0], hn[1]}, c2 = {cn[0], cn[1]};
                    *(f32x2*)&out[OUT_H_OFF + (size_t)b * HID + j0 + up * 2] = h2;
                    *(f32x2*)&out[OUT_C_OFF + (size_t)b * HID + j0 + up * 2] = c2;
                }
            }
            __syncthreads();
            if (tid == 0) st4(&F0[bid], (unsigned)(r + 1));
        }
    } else if (role == 1) {
        // ---------------- P1: xp1(r-1) = Wih1 @ hs0(r-1) + b1 ----------------
        load_wf(wb + WB_WIH1, j0, w, l15, q, wf);
        const int ucol = tid & 15, bq = tid >> 4;
        float bv[4];
#pragma unroll
        for (int gg = 0; gg < 4; gg++) bv[gg] = b1[gg * 1024 + j0 + ucol];
        for (int r = 1; r <= 512; ++r) {
            waitflags(F0, Fp, Fr, r, 0, r - 2, w, ln, &abortf);
            mm_ring(ring0 + (size_t)((r - 1) & 3) * 65536, wf, w, l15, q, P);
            __syncthreads();
            u16* xo = xp1 + (size_t)((r - 1) & 3) * 262144;
#pragma unroll
            for (int gg = 0; gg < 4; gg++) {
                const int col = gg * 16 + ucol;
                f32x4 s = *(const f32x4*)&P[0][col][bq * 4];
                s += *(const f32x4*)&P[1][col][bq * 4];
                s += *(const f32x4*)&P[2][col][bq * 4];
                s += *(const f32x4*)&P[3][col][bq * 4];
                s += bv[gg];
                const ull hw = (ull)f2bf(s.x) | ((ull)f2bf(s.y) << 16)
                             | ((ull)f2bf(s.z) << 32) | ((ull)f2bf(s.w) << 48);
                st8((ull*)(xo + (size_t)(gg * 1024 + j0 + ucol) * 64 + bq * 4), hw);
            }
            __syncthreads();
            if (tid == 0) st4(&Fp[bid & 63], (unsigned)(r + 1));
        }
    } else {
        // ---------------- R1: h1(r-2) = lstm(Whh1 @ h1(r-3) + xp1(r-2)) ----------------
        load_wf(wb + WB_WHH1, j0, w, l15, q, wf);
        const int up = tid & 7, bp = tid >> 3;
        float cst[2][2] = {{0.f, 0.f}, {0.f, 0.f}};
        for (int r = 2; r <= 513; ++r) {
            const int t = r - 2;
            waitflags(F0, Fp, Fr, 0, r, (r >= 3) ? r : 0, w, ln, &abortf);
            // xp1 loads (device-coherent), then h staging + MFMA
            unsigned xr2[4][2];
            const u16* xb = xp1 + (size_t)(t & 3) * 262144;
#pragma unroll
            for (int gg = 0; gg < 4; gg++)
#pragma unroll
                for (int u = 0; u < 2; u++)
                    xr2[gg][u] = ld4((const unsigned*)(xb +
                        (size_t)(gg * 1024 + j0 + up * 2 + u) * 64 + bp * 2));
            if (r > 2)
                mm_ring(ring1 + (size_t)((r - 3) & 3) * 65536, wf, w, l15, q, P);
            __syncthreads();
            f32x2 pre[4][2];
#pragma unroll
            for (int gg = 0; gg < 4; gg++)
#pragma unroll
                for (int u = 0; u < 2; u++) {
                    if (r > 2) {
                        const int col = gg * 16 + up * 2 + u;
                        f32x2 s = *(const f32x2*)&P[0][col][bp * 2];
                        s += *(const f32x2*)&P[1][col][bp * 2];
                        s += *(const f32x2*)&P[2][col][bp * 2];
                        s += *(const f32x2*)&P[3][col][bp * 2];
                        pre[gg][u] = s;
                    } else pre[gg][u] = 0.f;
                }
            u16* hout = ring1 + (size_t)((r - 2) & 3) * 65536;
#pragma unroll
            for (int bb = 0; bb < 2; bb++) {
                const int b = bp * 2 + bb;
                float hn[2], cn[2];
#pragma unroll
                for (int u = 0; u < 2; u++) {
                    const float pi = pre[0][u][bb] + xhalf(xr2[0][u], bb);
                    const float pf = pre[1][u][bb] + xhalf(xr2[1][u], bb) + 1.0f;
                    const float pg = pre[2][u][bb] + xhalf(xr2[2][u], bb);
                    const float po = pre[3][u][bb] + xhalf(xr2[3][u], bb);
                    const float cnew = sigm(pf) * cst[bb][u] + sigm(pi) * tanh_f(pg);
                    cst[bb][u] = cnew;
                    hn[u] = sigm(po) * tanh_f(cnew);
                    cn[u] = cnew;
                }
                const unsigned hw = (unsigned)f2bf(hn[0]) | ((unsigned)f2bf(hn[1]) << 16);
                st4((unsigned*)(hout + (size_t)b * HID + j0 + up * 2), hw);
                f32x2 g2 = {hn[0], hn[1]};
                *(f32x2*)&out[(size_t)b * 524288 + (size_t)t * 1024 + j0 + up * 2] = g2;
                if (r == 513) {
                    f32x2 h2 = {hn[0], hn[1]}, c2 = {cn[0], cn[1]};
                    *(f32x2*)&out[OUT_H_OFF + 65536 + (size_t)b * HID + j0 + up * 2] = h2;
                    *(f32x2*)&out[OUT_C_OFF + 65536 + (size_t)b * HID + j0 + up * 2] = c2;
                }
            }
            __syncthreads();
            if (tid == 0) st4(&Fr[bid & 63], (unsigned)(r + 1));
        }
    }
}

__global__ void diag(float* o, float v) { o[0] = v; }

extern "C" void kernel_launch(void* const* d_in, const int* in_sizes, int n_in,
                              void* d_out, int out_size, void* d_ws, size_t ws_size,
                              hipStream_t stream) {
    const int*   y    = (const int*)  d_in[0];
    const float* Emb  = (const float*)d_in[1];
    const float* Wih0 = (const float*)d_in[2];
    const float* Whh0 = (const float*)d_in[3];
    const float* b0   = (const float*)d_in[4];
    const float* Wih1 = (const float*)d_in[5];
    const float* Whh1 = (const float*)d_in[6];
    const float* b1   = (const float*)d_in[7];
    float* out = (float*)d_out;
    char* wsb = (char*)d_ws;

    if (ws_size < WS_NEEDED) {
        diag<<<1, 1, 0, stream>>>(out, (float)(ws_size >> 20));
        return;
    }

    u16* wb   = (u16*)wsb;
    u16* X    = (u16*)(wsb + WS_X_OFF);
    u16* Xp   = (u16*)(wsb + WS_XP_OFF);
    u16* ring0 = (u16*)(wsb + RING0_B);      // overlays Wih0 bf16 (dead after gemm0)
    u16* ring1 = (u16*)(wsb + RING1_B);
    u16* xp1   = (u16*)(wsb + XP1_B);
    unsigned* flags = (unsigned*)(wsb + FLAGS_B);

    prep_weights<<<1024, 256, 0, stream>>>(Wih0, Whh0, Wih1, Whh1, wb);
    gather_x<<<MTOK, 256, 0, stream>>>(y, Emb, X);
    gemm_bt<<<dim3(32, 256), 256, 0, stream>>>(X, wb + WB_WIH0, b0, Xp, MTOK, 4096, HID);
    init_flags<<<1, 256, 0, stream>>>(flags);
    pipeline<<<192, 256, 0, stream>>>(wb, Xp, b1, out, ring0, ring1, xp1, flags);
}